// Round 7
// baseline (158.977 us; speedup 1.0000x reference)
//
#include <hip/hip_runtime.h>

typedef __bf16 bf16;
typedef __bf16 bf16x2 __attribute__((ext_vector_type(2)));
typedef __bf16 bf16x4 __attribute__((ext_vector_type(4)));
typedef __bf16 bf16x8 __attribute__((ext_vector_type(8)));
typedef float  f32x4  __attribute__((ext_vector_type(4)));
typedef float  f32x16 __attribute__((ext_vector_type(16)));
typedef unsigned int u32x4 __attribute__((ext_vector_type(4)));

#define MFMA32(a,b,c) __builtin_amdgcn_mfma_f32_32x32x16_bf16((a),(b),(c),0,0,0)

#if __has_builtin(__builtin_amdgcn_exp2f)
#define EXP2(x) __builtin_amdgcn_exp2f(x)
#else
#define EXP2(x) exp2f(x)
#endif

__device__ __forceinline__ void gll16(const void* g, void* l) {
  __builtin_amdgcn_global_load_lds((const __attribute__((address_space(1))) unsigned int*)g,
                                   (__attribute__((address_space(3))) unsigned int*)l, 16, 0, 0);
}

__device__ __forceinline__ unsigned pk2(float a, float b) {
  bf16x2 t = { (bf16)a, (bf16)b };
  return __builtin_bit_cast(unsigned, t);
}

__device__ __forceinline__ void pl32swap(unsigned &x, unsigned &y) {
  asm("v_permlane32_swap_b32 %0, %1" : "+v"(x), "+v"(y));
}

// Problem constants: B=16, C=512, S=1024, heads=8, hd=64, groups=32
static constexpr int Cc = 512;
static constexpr int Ss = 1024;
#define QSCALE 0.18033688011112042f   // 1/sqrt(64) * log2(e), folded into Q

// ---------------- kernel 0: weight fp32 -> bf16 ----------------
__global__ __launch_bounds__(256) void k_wconv(const float* __restrict__ wq, const float* __restrict__ wp,
                                               bf16* __restrict__ wqb, bf16* __restrict__ wpb) {
  const int i = blockIdx.x * 256 + threadIdx.x;
  if (i * 4 < 786432) {
    float4 v = ((const float4*)wq)[i];
    bf16x4 o = { (bf16)v.x, (bf16)v.y, (bf16)v.z, (bf16)v.w };
    ((bf16x4*)wqb)[i] = o;
  } else {
    const int j = i - 786432 / 4;
    float4 v = ((const float4*)wp)[j];
    bf16x4 o = { (bf16)v.x, (bf16)v.y, (bf16)v.z, (bf16)v.w };
    ((bf16x4*)wpb)[j] = o;
  }
}

// ---------------- kernel 1: GroupNorm (single-pass, x cached in regs) ----------------
__global__ __launch_bounds__(256, 2) void k_gnorm(const float* __restrict__ x,
                                                  const float* __restrict__ gamma,
                                                  const float* __restrict__ beta,
                                                  bf16* __restrict__ ht) {
  const int g = blockIdx.x;
  const int b = blockIdx.y;
  const float* base = x + ((size_t)b * Cc + g * 16) * Ss;
  const int tid = threadIdx.x;

  f32x4 xr[16];
  float s = 0.f, sq = 0.f;
  #pragma unroll
  for (int k = 0; k < 16; ++k) {
    xr[k] = ((const f32x4*)base)[k * 256 + tid];
    s  += xr[k][0] + xr[k][1] + xr[k][2] + xr[k][3];
    sq += xr[k][0] * xr[k][0] + xr[k][1] * xr[k][1] + xr[k][2] * xr[k][2] + xr[k][3] * xr[k][3];
  }
  #pragma unroll
  for (int m = 1; m < 64; m <<= 1) { s += __shfl_xor(s, m); sq += __shfl_xor(sq, m); }
  __shared__ float red[8];
  if ((tid & 63) == 0) { red[tid >> 6] = s; red[4 + (tid >> 6)] = sq; }
  __syncthreads();
  const float stot = red[0] + red[1] + red[2] + red[3];
  const float sqt  = red[4] + red[5] + red[6] + red[7];
  const float mean = stot * (1.f / 16384.f);
  const float var  = sqt * (1.f / 16384.f) - mean * mean;
  const float rstd = rsqrtf(var + 1e-5f);

  float ga[16], bb[16];
  #pragma unroll
  for (int k = 0; k < 16; ++k) {
    ga[k] = gamma[g * 16 + k] * rstd;
    bb[k] = beta[g * 16 + k] - mean * ga[k];
  }

  bf16* dst0 = ht + ((size_t)b * Ss + tid * 4) * Cc + g * 16;
  #pragma unroll
  for (int j = 0; j < 4; ++j) {
    bf16x8 o0, o1;
    #pragma unroll
    for (int k = 0; k < 8; ++k)  o0[k] = (bf16)(xr[k][j] * ga[k] + bb[k]);
    #pragma unroll
    for (int k = 0; k < 8; ++k)  o1[k] = (bf16)(xr[8 + k][j] * ga[8 + k] + bb[8 + k]);
    bf16* d = dst0 + (size_t)j * Cc;
    *(bf16x8*)d = o0;
    *(bf16x8*)(d + 8) = o1;
  }
}

// ---------------- kernels 2 & 4: batched NT GEMM v2 ----------------
// 128x128 tile, BK=64, 32x32x16 MFMA, fragment-ordered LDS (conflict-free).
// C[b][o][s](+bias) = sum_c A[o][c] * Bt[b][s][c]
// A-chunk(mb,kb): lane l holds A[M0+mb*32+(l&31)][kt*64+kb*16+(l>>5)*8 ..+8]
// -> every fragment read is a contiguous 1KB chunk at lane*16: conflict-free.
template<int MODE>
__global__ __launch_bounds__(256, 4) void k_gemm(const bf16* __restrict__ Aw,
                                                 const bf16* __restrict__ Bt,
                                                 const float* __restrict__ bias,
                                                 bf16* __restrict__ qo, bf16* __restrict__ ko,
                                                 bf16* __restrict__ vo,
                                                 const float* __restrict__ xres,
                                                 float* __restrict__ out) {
  const int nt = blockIdx.x, mt = blockIdx.y, b = blockIdx.z;
  const int M0 = mt * 128, N0 = nt * 128;
  __shared__ __align__(16) bf16 lA[16 * 512];   // 16 chunks x 1KB
  __shared__ __align__(16) bf16 lB[16 * 512];
  const int tid = threadIdx.x;
  const int l = tid & 63, w = tid >> 6;
  const int wm = w >> 1, wn = w & 1;
  const int l31 = l & 31, h = l >> 5;
  const int ct = tid >> 6;                      // chunk-column this thread stages (kb)
  const bf16* Bb = Bt + (size_t)b * Ss * Cc;

  // staging source/dest (kt advances by 64 elements = 128B per K-tile)
  const char* asrc = (const char*)(Aw + (size_t)(M0 + l31) * 512 + ct * 16 + h * 8);
  const char* bsrc = (const char*)(Bb + (size_t)(N0 + l31) * 512 + ct * 16 + h * 8);
  char* adst = (char*)lA + ct * 1024 + l * 16;
  char* bdst = (char*)lB + ct * 1024 + l * 16;

  f32x16 acc[2][2];
  #pragma unroll
  for (int i = 0; i < 2; ++i)
    #pragma unroll
    for (int j = 0; j < 2; ++j)
      #pragma unroll
      for (int r = 0; r < 16; ++r) acc[i][j][r] = 0.f;

  for (int kt = 0; kt < 8; ++kt) {
    #pragma unroll
    for (int mb = 0; mb < 4; ++mb)
      gll16(asrc + (size_t)mb * 32768 + kt * 128, adst + mb * 4096);
    #pragma unroll
    for (int nb = 0; nb < 4; ++nb)
      gll16(bsrc + (size_t)nb * 32768 + kt * 128, bdst + nb * 4096);
    __syncthreads();
    #pragma unroll
    for (int kb = 0; kb < 4; ++kb) {
      bf16x8 a0 = *(const bf16x8*)((const char*)lA + ((wm * 2 + 0) * 4 + kb) * 1024 + l * 16);
      bf16x8 a1 = *(const bf16x8*)((const char*)lA + ((wm * 2 + 1) * 4 + kb) * 1024 + l * 16);
      bf16x8 b0 = *(const bf16x8*)((const char*)lB + ((wn * 2 + 0) * 4 + kb) * 1024 + l * 16);
      bf16x8 b1 = *(const bf16x8*)((const char*)lB + ((wn * 2 + 1) * 4 + kb) * 1024 + l * 16);
      acc[0][0] = MFMA32(a0, b0, acc[0][0]);
      acc[0][1] = MFMA32(a0, b1, acc[0][1]);
      acc[1][0] = MFMA32(a1, b0, acc[1][0]);
      acc[1][1] = MFMA32(a1, b1, acc[1][1]);
    }
    __syncthreads();
  }

  // epilogue — D frag: col(N) = l31, row(M) = (reg&3) + 8*(reg>>2) + 4*h
  #pragma unroll
  for (int m = 0; m < 2; ++m) {
    const int ofr = M0 + wm * 64 + m * 32;      // 32-aligned M base of this frag row-block
    #pragma unroll
    for (int n = 0; n < 2; ++n) {
      const int sI = N0 + wn * 64 + n * 32 + l31;
      #pragma unroll
      for (int Qi = 0; Qi < 4; ++Qi) {
        const int rb = Qi * 8 + h * 4;          // row base within 32: + r (r=0..3)
        float v[4], bi[4];
        #pragma unroll
        for (int r = 0; r < 4; ++r) {
          v[r] = acc[m][n][Qi * 4 + r];
          bi[r] = bias[ofr + rb + r];
        }
        if (MODE == 0) {
          const int which = ofr >> 9;           // 0=q 1=k 2=v
          const int nh = (ofr >> 6) & 7;
          const int dbase = (ofr & 63) + rb;
          const size_t bh = (size_t)b * 8 + nh;
          if (which == 2) {
            #pragma unroll
            for (int r = 0; r < 4; ++r)
              vo[(bh * 64 + dbase + r) * 1024 + sI] = (bf16)(v[r] + bi[r]);
          } else {
            const float qs = which ? 1.f : QSCALE;
            bf16x4 pk = { (bf16)((v[0] + bi[0]) * qs), (bf16)((v[1] + bi[1]) * qs),
                          (bf16)((v[2] + bi[2]) * qs), (bf16)((v[3] + bi[3]) * qs) };
            bf16* dst = (which ? ko : qo) + (bh * 1024 + sI) * 64 + dbase;
            *(bf16x4*)dst = pk;
          }
        } else {
          #pragma unroll
          for (int r = 0; r < 4; ++r) {
            const size_t idx = ((size_t)b * 512 + ofr + rb + r) * 1024 + sI;
            out[idx] = xres[idx] + bi[r] + v[r];
          }
        }
      }
    }
  }
}

// ---------------- kernel 3: flash attention v5 (32x32x16, fragment-ordered LDS) ----------------
__global__ __launch_bounds__(512, 3) void k_attn(const bf16* __restrict__ qT,
                                                 const bf16* __restrict__ kT,
                                                 const bf16* __restrict__ vv,
                                                 bf16* __restrict__ ao) {
  const int it = blockIdx.x, nh = blockIdx.y, b = blockIdx.z;
  const size_t bh = (size_t)b * 8 + nh;
  const char* kh = (const char*)(kT + bh * 65536);
  const char* vh = (const char*)(vv + bh * 65536);
  __shared__ __align__(16) char smem[32768];  // K 2x8K | V 2x8K
  const int tid = threadIdx.x;
  const int w = tid >> 6, l = tid & 63;
  const int l31 = l & 31, h = l >> 5;

  const int ct = tid >> 6, c3 = ct & 3, c2 = ct >> 2;
  const char* ksrc = kh + (size_t)(c2 * 32 + l31) * 128 + c3 * 32 + h * 16;   // +8192/tile
  const char* vsrc = vh + (size_t)(c2 * 32 + l31) * 2048 + c3 * 32 + h * 16;  // +128/tile
  char* lkdst = smem + tid * 16;
  char* lvdst = smem + 16384 + tid * 16;

  const bf16* qrow = qT + bh * 65536 + (size_t)(it * 256 + w * 32 + l31) * 64;
  bf16x8 qf[4];
  #pragma unroll
  for (int kq = 0; kq < 4; ++kq) qf[kq] = *(const bf16x8*)(qrow + kq * 16 + h * 8);

  gll16(ksrc, lkdst);
  gll16(vsrc, lvdst);

  f32x16 oacc[2];
  #pragma unroll
  for (int dt = 0; dt < 2; ++dt)
    #pragma unroll
    for (int r = 0; r < 16; ++r) oacc[dt][r] = 0.f;
  float lacc0 = 0.f, lacc1 = 0.f;

  __syncthreads();

  int cur = 0;
  for (int t = 0; t < 16; ++t) {
    if (t < 15) {
      gll16(ksrc + (size_t)(t + 1) * 8192, lkdst + (cur ^ 1) * 8192);
      gll16(vsrc + (size_t)(t + 1) * 128,  lvdst + (cur ^ 1) * 8192);
    }
    const char* lkc = smem + cur * 8192;
    const char* lvc = smem + 16384 + cur * 8192;

    f32x16 sf[2];
    #pragma unroll
    for (int r = 0; r < 16; ++r) { sf[0][r] = 0.f; sf[1][r] = 0.f; }
    __builtin_amdgcn_s_setprio(1);
    #pragma unroll
    for (int kq = 0; kq < 4; ++kq) {
      bf16x8 a0 = *(const bf16x8*)(lkc + kq * 1024 + l * 16);
      bf16x8 a1 = *(const bf16x8*)(lkc + (4 + kq) * 1024 + l * 16);
      sf[0] = MFMA32(a0, qf[kq], sf[0]);
      sf[1] = MFMA32(a1, qf[kq], sf[1]);
    }
    __builtin_amdgcn_s_setprio(0);

    unsigned pw[2][4][2];
    #pragma unroll
    for (int jt = 0; jt < 2; ++jt) {
      #pragma unroll
      for (int Qi = 0; Qi < 4; ++Qi) {
        const float p0 = EXP2(sf[jt][Qi * 4 + 0]);
        const float p1 = EXP2(sf[jt][Qi * 4 + 1]);
        const float p2 = EXP2(sf[jt][Qi * 4 + 2]);
        const float p3 = EXP2(sf[jt][Qi * 4 + 3]);
        lacc0 += p0 + p1; lacc1 += p2 + p3;
        pw[jt][Qi][0] = pk2(p0, p1);
        pw[jt][Qi][1] = pk2(p2, p3);
      }
    }

    bf16x8 pb[4];
    #pragma unroll
    for (int s = 0; s < 4; ++s) {
      const int jt = s >> 1, sq = s & 1;
      unsigned x0 = pw[jt][2 * sq][0], y0 = pw[jt][2 * sq + 1][0];
      unsigned x1 = pw[jt][2 * sq][1], y1 = pw[jt][2 * sq + 1][1];
      pl32swap(x0, y0);
      pl32swap(x1, y1);
      u32x4 wv = { x0, x1, y0, y1 };
      pb[s] = __builtin_bit_cast(bf16x8, wv);
    }

    __builtin_amdgcn_s_setprio(1);
    #pragma unroll
    for (int dt = 0; dt < 2; ++dt) {
      #pragma unroll
      for (int s = 0; s < 4; ++s) {
        bf16x8 av = *(const bf16x8*)(lvc + (dt * 4 + s) * 1024 + l * 16);
        oacc[dt] = MFMA32(av, pb[s], oacc[dt]);
      }
    }
    __builtin_amdgcn_s_setprio(0);
    __syncthreads();
    cur ^= 1;
  }

  float ls = lacc0 + lacc1;
  ls += __shfl_xor(ls, 32);
  const float rinv = 1.f / ls;

  bf16* aor = ao + ((size_t)b * 1024 + it * 256 + w * 32 + l31) * 512 + nh * 64;
  #pragma unroll
  for (int dt = 0; dt < 2; ++dt) {
    #pragma unroll
    for (int Qi = 0; Qi < 4; ++Qi) {
      bf16x4 o = { (bf16)(oacc[dt][Qi * 4 + 0] * rinv), (bf16)(oacc[dt][Qi * 4 + 1] * rinv),
                   (bf16)(oacc[dt][Qi * 4 + 2] * rinv), (bf16)(oacc[dt][Qi * 4 + 3] * rinv) };
      *(bf16x4*)(aor + dt * 32 + Qi * 8 + h * 4) = o;
    }
  }
}

extern "C" void kernel_launch(void* const* d_in, const int* in_sizes, int n_in,
                              void* d_out, int out_size, void* d_ws, size_t ws_size,
                              hipStream_t stream) {
  (void)in_sizes; (void)n_in; (void)out_size; (void)ws_size;
  const float* x   = (const float*)d_in[0];
  const float* gam = (const float*)d_in[1];
  const float* bet = (const float*)d_in[2];
  const float* wq  = (const float*)d_in[3];
  const float* bq  = (const float*)d_in[4];
  const float* wp  = (const float*)d_in[5];
  const float* bp  = (const float*)d_in[6];
  float* out = (float*)d_out;

  bf16* ws  = (bf16*)d_ws;
  bf16* ht  = ws;              // [16][1024][512]   (reused as attention output)
  bf16* qT  = ws + 8388608;    // [128][1024][64]
  bf16* kT  = ws + 16777216;   // [128][1024][64]
  bf16* vv  = ws + 25165824;   // [128][64][1024]
  bf16* wqb = ws + 33554432;   // [1536][512]
  bf16* wpb = ws + 34340864;   // [512][512]

  k_wconv<<<1024, 256, 0, stream>>>(wq, wp, wqb, wpb);
  k_gnorm<<<dim3(32, 16), 256, 0, stream>>>(x, gam, bet, ht);
  k_gemm<0><<<dim3(8, 12, 16), 256, 0, stream>>>(wqb, ht, bq, qT, kT, vv, nullptr, nullptr);
  k_attn<<<dim3(4, 8, 16), 512, 0, stream>>>(qT, kT, vv, ht);
  k_gemm<1><<<dim3(8, 4, 16), 256, 0, stream>>>(wpb, ht, bp, nullptr, nullptr, nullptr, x, out);
}

// Round 8
// 150.248 us; speedup vs baseline: 1.0581x; 1.0581x over previous
//
#include <hip/hip_runtime.h>

typedef __bf16 bf16;
typedef __bf16 bf16x2 __attribute__((ext_vector_type(2)));
typedef __bf16 bf16x4 __attribute__((ext_vector_type(4)));
typedef __bf16 bf16x8 __attribute__((ext_vector_type(8)));
typedef float  f32x4  __attribute__((ext_vector_type(4)));
typedef float  f32x16 __attribute__((ext_vector_type(16)));
typedef unsigned int u32x4 __attribute__((ext_vector_type(4)));

#define MFMA32(a,b,c) __builtin_amdgcn_mfma_f32_32x32x16_bf16((a),(b),(c),0,0,0)

#if __has_builtin(__builtin_amdgcn_exp2f)
#define EXP2(x) __builtin_amdgcn_exp2f(x)
#else
#define EXP2(x) exp2f(x)
#endif

__device__ __forceinline__ void gll16(const void* g, void* l) {
  __builtin_amdgcn_global_load_lds((const __attribute__((address_space(1))) unsigned int*)g,
                                   (__attribute__((address_space(3))) unsigned int*)l, 16, 0, 0);
}

__device__ __forceinline__ unsigned pk2(float a, float b) {
  bf16x2 t = { (bf16)a, (bf16)b };
  return __builtin_bit_cast(unsigned, t);
}

__device__ __forceinline__ void pl32swap(unsigned &x, unsigned &y) {
  asm("v_permlane32_swap_b32 %0, %1" : "+v"(x), "+v"(y));
}

// Problem constants: B=16, C=512, S=1024, heads=8, hd=64, groups=32
static constexpr int Cc = 512;
static constexpr int Ss = 1024;
#define QSCALE 0.18033688011112042f   // 1/sqrt(64) * log2(e), folded into Q

// ---------------- kernel 0: weight fp32 -> bf16 ----------------
__global__ __launch_bounds__(256) void k_wconv(const float* __restrict__ wq, const float* __restrict__ wp,
                                               bf16* __restrict__ wqb, bf16* __restrict__ wpb) {
  const int i = blockIdx.x * 256 + threadIdx.x;
  if (i * 4 < 786432) {
    float4 v = ((const float4*)wq)[i];
    bf16x4 o = { (bf16)v.x, (bf16)v.y, (bf16)v.z, (bf16)v.w };
    ((bf16x4*)wqb)[i] = o;
  } else {
    const int j = i - 786432 / 4;
    float4 v = ((const float4*)wp)[j];
    bf16x4 o = { (bf16)v.x, (bf16)v.y, (bf16)v.z, (bf16)v.w };
    ((bf16x4*)wpb)[j] = o;
  }
}

// ---------------- kernel 1: GroupNorm (single-pass, x cached in regs) ----------------
__global__ __launch_bounds__(256, 2) void k_gnorm(const float* __restrict__ x,
                                                  const float* __restrict__ gamma,
                                                  const float* __restrict__ beta,
                                                  bf16* __restrict__ ht) {
  const int g = blockIdx.x;
  const int b = blockIdx.y;
  const float* base = x + ((size_t)b * Cc + g * 16) * Ss;
  const int tid = threadIdx.x;

  f32x4 xr[16];
  float s = 0.f, sq = 0.f;
  #pragma unroll
  for (int k = 0; k < 16; ++k) {
    xr[k] = ((const f32x4*)base)[k * 256 + tid];
    s  += xr[k][0] + xr[k][1] + xr[k][2] + xr[k][3];
    sq += xr[k][0] * xr[k][0] + xr[k][1] * xr[k][1] + xr[k][2] * xr[k][2] + xr[k][3] * xr[k][3];
  }
  #pragma unroll
  for (int m = 1; m < 64; m <<= 1) { s += __shfl_xor(s, m); sq += __shfl_xor(sq, m); }
  __shared__ float red[8];
  if ((tid & 63) == 0) { red[tid >> 6] = s; red[4 + (tid >> 6)] = sq; }
  __syncthreads();
  const float stot = red[0] + red[1] + red[2] + red[3];
  const float sqt  = red[4] + red[5] + red[6] + red[7];
  const float mean = stot * (1.f / 16384.f);
  const float var  = sqt * (1.f / 16384.f) - mean * mean;
  const float rstd = rsqrtf(var + 1e-5f);

  float ga[16], bb[16];
  #pragma unroll
  for (int k = 0; k < 16; ++k) {
    ga[k] = gamma[g * 16 + k] * rstd;
    bb[k] = beta[g * 16 + k] - mean * ga[k];
  }

  bf16* dst0 = ht + ((size_t)b * Ss + tid * 4) * Cc + g * 16;
  #pragma unroll
  for (int j = 0; j < 4; ++j) {
    bf16x8 o0, o1;
    #pragma unroll
    for (int k = 0; k < 8; ++k)  o0[k] = (bf16)(xr[k][j] * ga[k] + bb[k]);
    #pragma unroll
    for (int k = 0; k < 8; ++k)  o1[k] = (bf16)(xr[8 + k][j] * ga[8 + k] + bb[8 + k]);
    bf16* d = dst0 + (size_t)j * Cc;
    *(bf16x8*)d = o0;
    *(bf16x8*)(d + 8) = o1;
  }
}

// ---------------- kernels 2 & 4: batched NT GEMM v3 ----------------
// 128x128 tile, BK=64, 32x32x16 MFMA, fragment-ordered LDS (conflict-free),
// DOUBLE-BUFFERED 2-phase schedule with counted vmcnt (loads in flight across
// barriers; no vmcnt(0) drain inside the loop).
template<int MODE>
__global__ __launch_bounds__(256, 2) void k_gemm(const bf16* __restrict__ Aw,
                                                 const bf16* __restrict__ Bt,
                                                 const float* __restrict__ bias,
                                                 bf16* __restrict__ qo, bf16* __restrict__ ko,
                                                 bf16* __restrict__ vo,
                                                 const float* __restrict__ xres,
                                                 float* __restrict__ out) {
  const int nt = blockIdx.x, mt = blockIdx.y, b = blockIdx.z;
  const int M0 = mt * 128, N0 = nt * 128;
  __shared__ __align__(16) bf16 lA[2][16 * 512];   // 2 x 16 chunks x 1KB
  __shared__ __align__(16) bf16 lB[2][16 * 512];
  const int tid = threadIdx.x;
  const int l = tid & 63, w = tid >> 6;
  const int wm = w >> 1, wn = w & 1;
  const int l31 = l & 31, h = l >> 5;
  const int ct = tid >> 6;                      // chunk-column this thread stages (kb)
  const bf16* Bb = Bt + (size_t)b * Ss * Cc;

  const char* asrc = (const char*)(Aw + (size_t)(M0 + l31) * 512 + ct * 16 + h * 8);
  const char* bsrc = (const char*)(Bb + (size_t)(N0 + l31) * 512 + ct * 16 + h * 8);
  const int dstoff = ct * 1024 + l * 16;

  f32x16 acc[2][2];
  #pragma unroll
  for (int i = 0; i < 2; ++i)
    #pragma unroll
    for (int j = 0; j < 2; ++j)
      #pragma unroll
      for (int r = 0; r < 16; ++r) acc[i][j][r] = 0.f;

  // prologue: stage tile 0 into buffer 0 (8 loads/thread)
  #pragma unroll
  for (int mb = 0; mb < 4; ++mb)
    gll16(asrc + (size_t)mb * 32768, (char*)lA[0] + dstoff + mb * 4096);
  #pragma unroll
  for (int nb = 0; nb < 4; ++nb)
    gll16(bsrc + (size_t)nb * 32768, (char*)lB[0] + dstoff + nb * 4096);

  #pragma unroll
  for (int kt = 0; kt < 8; ++kt) {
    const int cur = kt & 1;
    if (kt < 7) {  // issue tile kt+1 into the other buffer (stays in flight across barrier)
      #pragma unroll
      for (int mb = 0; mb < 4; ++mb)
        gll16(asrc + (size_t)mb * 32768 + (kt + 1) * 128, (char*)lA[cur ^ 1] + dstoff + mb * 4096);
      #pragma unroll
      for (int nb = 0; nb < 4; ++nb)
        gll16(bsrc + (size_t)nb * 32768 + (kt + 1) * 128, (char*)lB[cur ^ 1] + dstoff + nb * 4096);
      asm volatile("s_waitcnt vmcnt(8)" ::: "memory");   // tile-kt loads done; kt+1's 8 in flight
    } else {
      asm volatile("s_waitcnt vmcnt(0)" ::: "memory");
    }
    __builtin_amdgcn_s_barrier();                        // union of all waves' tile-kt writes
    __builtin_amdgcn_sched_barrier(0);

    __builtin_amdgcn_s_setprio(1);
    #pragma unroll
    for (int kb = 0; kb < 4; ++kb) {
      bf16x8 a0 = *(const bf16x8*)((const char*)lA[cur] + ((wm * 2 + 0) * 4 + kb) * 1024 + l * 16);
      bf16x8 a1 = *(const bf16x8*)((const char*)lA[cur] + ((wm * 2 + 1) * 4 + kb) * 1024 + l * 16);
      bf16x8 b0 = *(const bf16x8*)((const char*)lB[cur] + ((wn * 2 + 0) * 4 + kb) * 1024 + l * 16);
      bf16x8 b1 = *(const bf16x8*)((const char*)lB[cur] + ((wn * 2 + 1) * 4 + kb) * 1024 + l * 16);
      acc[0][0] = MFMA32(a0, b0, acc[0][0]);
      acc[0][1] = MFMA32(a0, b1, acc[0][1]);
      acc[1][0] = MFMA32(a1, b0, acc[1][0]);
      acc[1][1] = MFMA32(a1, b1, acc[1][1]);
    }
    __builtin_amdgcn_s_setprio(0);
    if (kt < 7) {  // reads of buf[cur] done before anyone stages tile kt+2 into it
      asm volatile("s_waitcnt lgkmcnt(0)" ::: "memory");
      __builtin_amdgcn_s_barrier();
    }
  }

  // epilogue — D frag: col(N) = l31, row(M) = (reg&3) + 8*(reg>>2) + 4*h
  #pragma unroll
  for (int m = 0; m < 2; ++m) {
    const int ofr = M0 + wm * 64 + m * 32;
    #pragma unroll
    for (int n = 0; n < 2; ++n) {
      const int sI = N0 + wn * 64 + n * 32 + l31;
      #pragma unroll
      for (int Qi = 0; Qi < 4; ++Qi) {
        const int rb = Qi * 8 + h * 4;
        float v[4], bi[4];
        #pragma unroll
        for (int r = 0; r < 4; ++r) {
          v[r] = acc[m][n][Qi * 4 + r];
          bi[r] = bias[ofr + rb + r];
        }
        if (MODE == 0) {
          const int which = ofr >> 9;           // 0=q 1=k 2=v
          const int nh = (ofr >> 6) & 7;
          const int dbase = (ofr & 63) + rb;
          const size_t bh = (size_t)b * 8 + nh;
          if (which == 2) {
            #pragma unroll
            for (int r = 0; r < 4; ++r)
              vo[(bh * 64 + dbase + r) * 1024 + sI] = (bf16)(v[r] + bi[r]);
          } else {
            const float qs = which ? 1.f : QSCALE;
            bf16x4 pk = { (bf16)((v[0] + bi[0]) * qs), (bf16)((v[1] + bi[1]) * qs),
                          (bf16)((v[2] + bi[2]) * qs), (bf16)((v[3] + bi[3]) * qs) };
            bf16* dst = (which ? ko : qo) + (bh * 1024 + sI) * 64 + dbase;
            *(bf16x4*)dst = pk;
          }
        } else {
          #pragma unroll
          for (int r = 0; r < 4; ++r) {
            const size_t idx = ((size_t)b * 512 + ofr + rb + r) * 1024 + sI;
            out[idx] = xres[idx] + bi[r] + v[r];
          }
        }
      }
    }
  }
}

// ---------------- kernel 3: flash attention v5 (32x32x16, fragment-ordered LDS) ----------------
__global__ __launch_bounds__(512, 3) void k_attn(const bf16* __restrict__ qT,
                                                 const bf16* __restrict__ kT,
                                                 const bf16* __restrict__ vv,
                                                 bf16* __restrict__ ao) {
  const int it = blockIdx.x, nh = blockIdx.y, b = blockIdx.z;
  const size_t bh = (size_t)b * 8 + nh;
  const char* kh = (const char*)(kT + bh * 65536);
  const char* vh = (const char*)(vv + bh * 65536);
  __shared__ __align__(16) char smem[32768];  // K 2x8K | V 2x8K
  const int tid = threadIdx.x;
  const int w = tid >> 6, l = tid & 63;
  const int l31 = l & 31, h = l >> 5;

  const int ct = tid >> 6, c3 = ct & 3, c2 = ct >> 2;
  const char* ksrc = kh + (size_t)(c2 * 32 + l31) * 128 + c3 * 32 + h * 16;   // +8192/tile
  const char* vsrc = vh + (size_t)(c2 * 32 + l31) * 2048 + c3 * 32 + h * 16;  // +128/tile
  char* lkdst = smem + tid * 16;
  char* lvdst = smem + 16384 + tid * 16;

  const bf16* qrow = qT + bh * 65536 + (size_t)(it * 256 + w * 32 + l31) * 64;
  bf16x8 qf[4];
  #pragma unroll
  for (int kq = 0; kq < 4; ++kq) qf[kq] = *(const bf16x8*)(qrow + kq * 16 + h * 8);

  gll16(ksrc, lkdst);
  gll16(vsrc, lvdst);

  f32x16 oacc[2];
  #pragma unroll
  for (int dt = 0; dt < 2; ++dt)
    #pragma unroll
    for (int r = 0; r < 16; ++r) oacc[dt][r] = 0.f;
  float lacc0 = 0.f, lacc1 = 0.f;

  __syncthreads();

  int cur = 0;
  for (int t = 0; t < 16; ++t) {
    if (t < 15) {
      gll16(ksrc + (size_t)(t + 1) * 8192, lkdst + (cur ^ 1) * 8192);
      gll16(vsrc + (size_t)(t + 1) * 128,  lvdst + (cur ^ 1) * 8192);
    }
    const char* lkc = smem + cur * 8192;
    const char* lvc = smem + 16384 + cur * 8192;

    f32x16 sf[2];
    #pragma unroll
    for (int r = 0; r < 16; ++r) { sf[0][r] = 0.f; sf[1][r] = 0.f; }
    __builtin_amdgcn_s_setprio(1);
    #pragma unroll
    for (int kq = 0; kq < 4; ++kq) {
      bf16x8 a0 = *(const bf16x8*)(lkc + kq * 1024 + l * 16);
      bf16x8 a1 = *(const bf16x8*)(lkc + (4 + kq) * 1024 + l * 16);
      sf[0] = MFMA32(a0, qf[kq], sf[0]);
      sf[1] = MFMA32(a1, qf[kq], sf[1]);
    }
    __builtin_amdgcn_s_setprio(0);

    unsigned pw[2][4][2];
    #pragma unroll
    for (int jt = 0; jt < 2; ++jt) {
      #pragma unroll
      for (int Qi = 0; Qi < 4; ++Qi) {
        const float p0 = EXP2(sf[jt][Qi * 4 + 0]);
        const float p1 = EXP2(sf[jt][Qi * 4 + 1]);
        const float p2 = EXP2(sf[jt][Qi * 4 + 2]);
        const float p3 = EXP2(sf[jt][Qi * 4 + 3]);
        lacc0 += p0 + p1; lacc1 += p2 + p3;
        pw[jt][Qi][0] = pk2(p0, p1);
        pw[jt][Qi][1] = pk2(p2, p3);
      }
    }

    bf16x8 pb[4];
    #pragma unroll
    for (int s = 0; s < 4; ++s) {
      const int jt = s >> 1, sq = s & 1;
      unsigned x0 = pw[jt][2 * sq][0], y0 = pw[jt][2 * sq + 1][0];
      unsigned x1 = pw[jt][2 * sq][1], y1 = pw[jt][2 * sq + 1][1];
      pl32swap(x0, y0);
      pl32swap(x1, y1);
      u32x4 wv = { x0, x1, y0, y1 };
      pb[s] = __builtin_bit_cast(bf16x8, wv);
    }

    __builtin_amdgcn_s_setprio(1);
    #pragma unroll
    for (int dt = 0; dt < 2; ++dt) {
      #pragma unroll
      for (int s = 0; s < 4; ++s) {
        bf16x8 av = *(const bf16x8*)(lvc + (dt * 4 + s) * 1024 + l * 16);
        oacc[dt] = MFMA32(av, pb[s], oacc[dt]);
      }
    }
    __builtin_amdgcn_s_setprio(0);
    __syncthreads();
    cur ^= 1;
  }

  float ls = lacc0 + lacc1;
  ls += __shfl_xor(ls, 32);
  const float rinv = 1.f / ls;

  bf16* aor = ao + ((size_t)b * 1024 + it * 256 + w * 32 + l31) * 512 + nh * 64;
  #pragma unroll
  for (int dt = 0; dt < 2; ++dt) {
    #pragma unroll
    for (int Qi = 0; Qi < 4; ++Qi) {
      bf16x4 o = { (bf16)(oacc[dt][Qi * 4 + 0] * rinv), (bf16)(oacc[dt][Qi * 4 + 1] * rinv),
                   (bf16)(oacc[dt][Qi * 4 + 2] * rinv), (bf16)(oacc[dt][Qi * 4 + 3] * rinv) };
      *(bf16x4*)(aor + dt * 32 + Qi * 8 + h * 4) = o;
    }
  }
}

extern "C" void kernel_launch(void* const* d_in, const int* in_sizes, int n_in,
                              void* d_out, int out_size, void* d_ws, size_t ws_size,
                              hipStream_t stream) {
  (void)in_sizes; (void)n_in; (void)out_size; (void)ws_size;
  const float* x   = (const float*)d_in[0];
  const float* gam = (const float*)d_in[1];
  const float* bet = (const float*)d_in[2];
  const float* wq  = (const float*)d_in[3];
  const float* bq  = (const float*)d_in[4];
  const float* wp  = (const float*)d_in[5];
  const float* bp  = (const float*)d_in[6];
  float* out = (float*)d_out;

  bf16* ws  = (bf16*)d_ws;
  bf16* ht  = ws;              // [16][1024][512]   (reused as attention output)
  bf16* qT  = ws + 8388608;    // [128][1024][64]
  bf16* kT  = ws + 16777216;   // [128][1024][64]
  bf16* vv  = ws + 25165824;   // [128][64][1024]
  bf16* wqb = ws + 33554432;   // [1536][512]
  bf16* wpb = ws + 34340864;   // [512][512]

  k_wconv<<<1024, 256, 0, stream>>>(wq, wp, wqb, wpb);
  k_gnorm<<<dim3(32, 16), 256, 0, stream>>>(x, gam, bet, ht);
  k_gemm<0><<<dim3(8, 12, 16), 256, 0, stream>>>(wqb, ht, bq, qT, kT, vv, nullptr, nullptr);
  k_attn<<<dim3(4, 8, 16), 512, 0, stream>>>(qT, kT, vv, ht);
  k_gemm<1><<<dim3(8, 4, 16), 256, 0, stream>>>(wpb, ht, bp, nullptr, nullptr, nullptr, x, out);
}

// Round 10
// 124.394 us; speedup vs baseline: 1.2780x; 1.2078x over previous
//
#include <hip/hip_runtime.h>

typedef __bf16 bf16;
typedef __bf16 bf16x2 __attribute__((ext_vector_type(2)));
typedef __bf16 bf16x4 __attribute__((ext_vector_type(4)));
typedef __bf16 bf16x8 __attribute__((ext_vector_type(8)));
typedef float  f32x4  __attribute__((ext_vector_type(4)));
typedef float  f32x16 __attribute__((ext_vector_type(16)));
typedef unsigned int u32x4 __attribute__((ext_vector_type(4)));

#define MFMA32(a,b,c) __builtin_amdgcn_mfma_f32_32x32x16_bf16((a),(b),(c),0,0,0)

#if __has_builtin(__builtin_amdgcn_exp2f)
#define EXP2(x) __builtin_amdgcn_exp2f(x)
#else
#define EXP2(x) exp2f(x)
#endif

__device__ __forceinline__ void gll16(const void* g, void* l) {
  __builtin_amdgcn_global_load_lds((const __attribute__((address_space(1))) unsigned int*)g,
                                   (__attribute__((address_space(3))) unsigned int*)l, 16, 0, 0);
}

__device__ __forceinline__ unsigned pk2(float a, float b) {
  bf16x2 t = { (bf16)a, (bf16)b };
  return __builtin_bit_cast(unsigned, t);
}

__device__ __forceinline__ void pl32swap(unsigned &x, unsigned &y) {
  asm("v_permlane32_swap_b32 %0, %1" : "+v"(x), "+v"(y));
}

// Problem constants: B=16, C=512, S=1024, heads=8, hd=64, groups=32
static constexpr int Cc = 512;
static constexpr int Ss = 1024;
#define QSCALE 0.18033688011112042f   // 1/sqrt(64) * log2(e), folded into Q

// ---------------- kernel 0: weight fp32 -> bf16 ----------------
__global__ __launch_bounds__(256) void k_wconv(const float* __restrict__ wq, const float* __restrict__ wp,
                                               bf16* __restrict__ wqb, bf16* __restrict__ wpb) {
  const int i = blockIdx.x * 256 + threadIdx.x;
  if (i * 4 < 786432) {
    float4 v = ((const float4*)wq)[i];
    bf16x4 o = { (bf16)v.x, (bf16)v.y, (bf16)v.z, (bf16)v.w };
    ((bf16x4*)wqb)[i] = o;
  } else {
    const int j = i - 786432 / 4;
    float4 v = ((const float4*)wp)[j];
    bf16x4 o = { (bf16)v.x, (bf16)v.y, (bf16)v.z, (bf16)v.w };
    ((bf16x4*)wpb)[j] = o;
  }
}

// ---------------- kernel 1: GroupNorm (single-pass, x cached in regs) ----------------
__global__ __launch_bounds__(256, 2) void k_gnorm(const float* __restrict__ x,
                                                  const float* __restrict__ gamma,
                                                  const float* __restrict__ beta,
                                                  bf16* __restrict__ ht) {
  const int g = blockIdx.x;
  const int b = blockIdx.y;
  const float* base = x + ((size_t)b * Cc + g * 16) * Ss;
  const int tid = threadIdx.x;

  f32x4 xr[16];
  float s = 0.f, sq = 0.f;
  #pragma unroll
  for (int k = 0; k < 16; ++k) {
    xr[k] = ((const f32x4*)base)[k * 256 + tid];
    s  += xr[k][0] + xr[k][1] + xr[k][2] + xr[k][3];
    sq += xr[k][0] * xr[k][0] + xr[k][1] * xr[k][1] + xr[k][2] * xr[k][2] + xr[k][3] * xr[k][3];
  }
  #pragma unroll
  for (int m = 1; m < 64; m <<= 1) { s += __shfl_xor(s, m); sq += __shfl_xor(sq, m); }
  __shared__ float red[8];
  if ((tid & 63) == 0) { red[tid >> 6] = s; red[4 + (tid >> 6)] = sq; }
  __syncthreads();
  const float stot = red[0] + red[1] + red[2] + red[3];
  const float sqt  = red[4] + red[5] + red[6] + red[7];
  const float mean = stot * (1.f / 16384.f);
  const float var  = sqt * (1.f / 16384.f) - mean * mean;
  const float rstd = rsqrtf(var + 1e-5f);

  float ga[16], bb[16];
  #pragma unroll
  for (int k = 0; k < 16; ++k) {
    ga[k] = gamma[g * 16 + k] * rstd;
    bb[k] = beta[g * 16 + k] - mean * ga[k];
  }

  bf16* dst0 = ht + ((size_t)b * Ss + tid * 4) * Cc + g * 16;
  #pragma unroll
  for (int j = 0; j < 4; ++j) {
    bf16x8 o0, o1;
    #pragma unroll
    for (int k = 0; k < 8; ++k)  o0[k] = (bf16)(xr[k][j] * ga[k] + bb[k]);
    #pragma unroll
    for (int k = 0; k < 8; ++k)  o1[k] = (bf16)(xr[8 + k][j] * ga[8 + k] + bb[8 + k]);
    bf16* d = dst0 + (size_t)j * Cc;
    *(bf16x8*)d = o0;
    *(bf16x8*)(d + 8) = o1;
  }
}

// ---------------- kernels 2 & 4: batched NT GEMM v4 ----------------
// 128x128 tile, BK=64, 32x32x16 MFMA, double-buffered counted-vmcnt schedule.
// T2 XOR-swizzle staging: COALESCED global reads (full 128B rows) with the
// 16B chunk column pre-swizzled c_src = c ^ (row&7); LDS row-major
// [128][128B]; ds_read_b128 applies the same XOR -> bank floor, no 16-way.
template<int MODE>
__global__ __launch_bounds__(256, 2) void k_gemm(const bf16* __restrict__ Aw,
                                                 const bf16* __restrict__ Bt,
                                                 const float* __restrict__ bias,
                                                 bf16* __restrict__ qo, bf16* __restrict__ ko,
                                                 bf16* __restrict__ vo,
                                                 const float* __restrict__ xres,
                                                 float* __restrict__ out) {
  const int nt = blockIdx.x, mt = blockIdx.y, b = blockIdx.z;
  const int M0 = mt * 128, N0 = nt * 128;
  __shared__ __align__(16) char lA[2][16384];   // [buf][row*128 + swizzled col]
  __shared__ __align__(16) char lB[2][16384];
  const int tid = threadIdx.x;
  const int l = tid & 63, w = tid >> 6;
  const int wm = w >> 1, wn = w & 1;
  const int l31 = l & 31, h = l >> 5;
  const bf16* Bb = Bt + (size_t)b * Ss * Cc;

  // staging: thread covers row r8 = tid>>3 (of each 32-row group p), chunk c8.
  // global src chunk = c8 ^ (r8&7)  (inverse swizzle); LDS dst linear tid*16.
  const int r8 = tid >> 3, c8 = tid & 7;
  const int csw = (c8 ^ (r8 & 7)) * 16;
  const char* asrc = (const char*)Aw + (size_t)(M0 + r8) * 1024 + csw;  // +p*32768, +kt*128
  const char* bsrc = (const char*)Bb + (size_t)(N0 + r8) * 1024 + csw;
  const int dstoff = tid * 16;                                          // +p*4096

  f32x16 acc[2][2];
  #pragma unroll
  for (int i = 0; i < 2; ++i)
    #pragma unroll
    for (int j = 0; j < 2; ++j)
      #pragma unroll
      for (int r = 0; r < 16; ++r) acc[i][j][r] = 0.f;

  // fragment read offsets: row = (w?*2+m)*32 + l31, chunk c16 = kb*2+h,
  // byte = row*128 + ((c16 ^ (l31&7)) * 16)
  const int sw7 = l31 & 7;

  // prologue: stage tile 0 into buffer 0 (8 loads/thread)
  #pragma unroll
  for (int p = 0; p < 4; ++p)
    gll16(asrc + (size_t)p * 32768, (char*)lA[0] + dstoff + p * 4096);
  #pragma unroll
  for (int p = 0; p < 4; ++p)
    gll16(bsrc + (size_t)p * 32768, (char*)lB[0] + dstoff + p * 4096);

  #pragma unroll
  for (int kt = 0; kt < 8; ++kt) {
    const int cur = kt & 1;
    if (kt < 7) {  // issue tile kt+1 into the other buffer (stays in flight across barrier)
      #pragma unroll
      for (int p = 0; p < 4; ++p)
        gll16(asrc + (size_t)p * 32768 + (kt + 1) * 128, (char*)lA[cur ^ 1] + dstoff + p * 4096);
      #pragma unroll
      for (int p = 0; p < 4; ++p)
        gll16(bsrc + (size_t)p * 32768 + (kt + 1) * 128, (char*)lB[cur ^ 1] + dstoff + p * 4096);
      asm volatile("s_waitcnt vmcnt(8)" ::: "memory");   // tile-kt loads done; kt+1's 8 in flight
    } else {
      asm volatile("s_waitcnt vmcnt(0)" ::: "memory");
    }
    __builtin_amdgcn_s_barrier();                        // union of all waves' tile-kt writes
    __builtin_amdgcn_sched_barrier(0);

    __builtin_amdgcn_s_setprio(1);
    #pragma unroll
    for (int kb = 0; kb < 4; ++kb) {
      const int cA0 = ((kb * 2 + h) ^ sw7) * 16;
      const int rA0 = (wm * 2 + 0) * 32 + l31, rA1 = (wm * 2 + 1) * 32 + l31;
      const int rB0 = (wn * 2 + 0) * 32 + l31, rB1 = (wn * 2 + 1) * 32 + l31;
      bf16x8 a0 = *(const bf16x8*)((const char*)lA[cur] + rA0 * 128 + cA0);
      bf16x8 a1 = *(const bf16x8*)((const char*)lA[cur] + rA1 * 128 + cA0);
      bf16x8 b0 = *(const bf16x8*)((const char*)lB[cur] + rB0 * 128 + cA0);
      bf16x8 b1 = *(const bf16x8*)((const char*)lB[cur] + rB1 * 128 + cA0);
      acc[0][0] = MFMA32(a0, b0, acc[0][0]);
      acc[0][1] = MFMA32(a0, b1, acc[0][1]);
      acc[1][0] = MFMA32(a1, b0, acc[1][0]);
      acc[1][1] = MFMA32(a1, b1, acc[1][1]);
    }
    __builtin_amdgcn_s_setprio(0);
    if (kt < 7) {  // reads of buf[cur] done before anyone stages tile kt+2 into it
      asm volatile("s_waitcnt lgkmcnt(0)" ::: "memory");
      __builtin_amdgcn_s_barrier();
    }
  }

  // epilogue — D frag: col(N) = l31, row(M) = (reg&3) + 8*(reg>>2) + 4*h
  #pragma unroll
  for (int m = 0; m < 2; ++m) {
    const int ofr = M0 + wm * 64 + m * 32;
    #pragma unroll
    for (int n = 0; n < 2; ++n) {
      const int sI = N0 + wn * 64 + n * 32 + l31;
      #pragma unroll
      for (int Qi = 0; Qi < 4; ++Qi) {
        const int rb = Qi * 8 + h * 4;
        float v[4], bi[4];
        #pragma unroll
        for (int r = 0; r < 4; ++r) {
          v[r] = acc[m][n][Qi * 4 + r];
          bi[r] = bias[ofr + rb + r];
        }
        if (MODE == 0) {
          const int which = ofr >> 9;           // 0=q 1=k 2=v
          const int nh = (ofr >> 6) & 7;
          const int dbase = (ofr & 63) + rb;
          const size_t bh = (size_t)b * 8 + nh;
          if (which == 2) {
            #pragma unroll
            for (int r = 0; r < 4; ++r)
              vo[(bh * 64 + dbase + r) * 1024 + sI] = (bf16)(v[r] + bi[r]);
          } else {
            const float qs = which ? 1.f : QSCALE;
            bf16x4 pk = { (bf16)((v[0] + bi[0]) * qs), (bf16)((v[1] + bi[1]) * qs),
                          (bf16)((v[2] + bi[2]) * qs), (bf16)((v[3] + bi[3]) * qs) };
            bf16* dst = (which ? ko : qo) + (bh * 1024 + sI) * 64 + dbase;
            *(bf16x4*)dst = pk;
          }
        } else {
          #pragma unroll
          for (int r = 0; r < 4; ++r) {
            const size_t idx = ((size_t)b * 512 + ofr + rb + r) * 1024 + sI;
            out[idx] = xres[idx] + bi[r] + v[r];
          }
        }
      }
    }
  }
}

// ---------------- kernel 3: flash attention v5 (32x32x16, fragment-ordered LDS) ----------------
__global__ __launch_bounds__(512, 3) void k_attn(const bf16* __restrict__ qT,
                                                 const bf16* __restrict__ kT,
                                                 const bf16* __restrict__ vv,
                                                 bf16* __restrict__ ao) {
  const int it = blockIdx.x, nh = blockIdx.y, b = blockIdx.z;
  const size_t bh = (size_t)b * 8 + nh;
  const char* kh = (const char*)(kT + bh * 65536);
  const char* vh = (const char*)(vv + bh * 65536);
  __shared__ __align__(16) char smem[32768];  // K 2x8K | V 2x8K
  const int tid = threadIdx.x;
  const int w = tid >> 6, l = tid & 63;
  const int l31 = l & 31, h = l >> 5;

  const int ct = tid >> 6, c3 = ct & 3, c2 = ct >> 2;
  const char* ksrc = kh + (size_t)(c2 * 32 + l31) * 128 + c3 * 32 + h * 16;   // +8192/tile
  const char* vsrc = vh + (size_t)(c2 * 32 + l31) * 2048 + c3 * 32 + h * 16;  // +128/tile
  char* lkdst = smem + tid * 16;
  char* lvdst = smem + 16384 + tid * 16;

  const bf16* qrow = qT + bh * 65536 + (size_t)(it * 256 + w * 32 + l31) * 64;
  bf16x8 qf[4];
  #pragma unroll
  for (int kq = 0; kq < 4; ++kq) qf[kq] = *(const bf16x8*)(qrow + kq * 16 + h * 8);

  gll16(ksrc, lkdst);
  gll16(vsrc, lvdst);

  f32x16 oacc[2];
  #pragma unroll
  for (int dt = 0; dt < 2; ++dt)
    #pragma unroll
    for (int r = 0; r < 16; ++r) oacc[dt][r] = 0.f;
  float lacc0 = 0.f, lacc1 = 0.f;

  __syncthreads();

  int cur = 0;
  for (int t = 0; t < 16; ++t) {
    if (t < 15) {
      gll16(ksrc + (size_t)(t + 1) * 8192, lkdst + (cur ^ 1) * 8192);
      gll16(vsrc + (size_t)(t + 1) * 128,  lvdst + (cur ^ 1) * 8192);
    }
    const char* lkc = smem + cur * 8192;
    const char* lvc = smem + 16384 + cur * 8192;

    f32x16 sf[2];
    #pragma unroll
    for (int r = 0; r < 16; ++r) { sf[0][r] = 0.f; sf[1][r] = 0.f; }
    __builtin_amdgcn_s_setprio(1);
    #pragma unroll
    for (int kq = 0; kq < 4; ++kq) {
      bf16x8 a0 = *(const bf16x8*)(lkc + kq * 1024 + l * 16);
      bf16x8 a1 = *(const bf16x8*)(lkc + (4 + kq) * 1024 + l * 16);
      sf[0] = MFMA32(a0, qf[kq], sf[0]);
      sf[1] = MFMA32(a1, qf[kq], sf[1]);
    }
    __builtin_amdgcn_s_setprio(0);

    unsigned pw[2][4][2];
    #pragma unroll
    for (int jt = 0; jt < 2; ++jt) {
      #pragma unroll
      for (int Qi = 0; Qi < 4; ++Qi) {
        const float p0 = EXP2(sf[jt][Qi * 4 + 0]);
        const float p1 = EXP2(sf[jt][Qi * 4 + 1]);
        const float p2 = EXP2(sf[jt][Qi * 4 + 2]);
        const float p3 = EXP2(sf[jt][Qi * 4 + 3]);
        lacc0 += p0 + p1; lacc1 += p2 + p3;
        pw[jt][Qi][0] = pk2(p0, p1);
        pw[jt][Qi][1] = pk2(p2, p3);
      }
    }

    bf16x8 pb[4];
    #pragma unroll
    for (int s = 0; s < 4; ++s) {
      const int jt = s >> 1, sq = s & 1;
      unsigned x0 = pw[jt][2 * sq][0], y0 = pw[jt][2 * sq + 1][0];
      unsigned x1 = pw[jt][2 * sq][1], y1 = pw[jt][2 * sq + 1][1];
      pl32swap(x0, y0);
      pl32swap(x1, y1);
      u32x4 wv = { x0, x1, y0, y1 };
      pb[s] = __builtin_bit_cast(bf16x8, wv);
    }

    __builtin_amdgcn_s_setprio(1);
    #pragma unroll
    for (int dt = 0; dt < 2; ++dt) {
      #pragma unroll
      for (int s = 0; s < 4; ++s) {
        bf16x8 av = *(const bf16x8*)(lvc + (dt * 4 + s) * 1024 + l * 16);
        oacc[dt] = MFMA32(av, pb[s], oacc[dt]);
      }
    }
    __builtin_amdgcn_s_setprio(0);
    __syncthreads();
    cur ^= 1;
  }

  float ls = lacc0 + lacc1;
  ls += __shfl_xor(ls, 32);
  const float rinv = 1.f / ls;

  bf16* aor = ao + ((size_t)b * 1024 + it * 256 + w * 32 + l31) * 512 + nh * 64;
  #pragma unroll
  for (int dt = 0; dt < 2; ++dt) {
    #pragma unroll
    for (int Qi = 0; Qi < 4; ++Qi) {
      bf16x4 o = { (bf16)(oacc[dt][Qi * 4 + 0] * rinv), (bf16)(oacc[dt][Qi * 4 + 1] * rinv),
                   (bf16)(oacc[dt][Qi * 4 + 2] * rinv), (bf16)(oacc[dt][Qi * 4 + 3] * rinv) };
      *(bf16x4*)(aor + dt * 32 + Qi * 8 + h * 4) = o;
    }
  }
}

extern "C" void kernel_launch(void* const* d_in, const int* in_sizes, int n_in,
                              void* d_out, int out_size, void* d_ws, size_t ws_size,
                              hipStream_t stream) {
  (void)in_sizes; (void)n_in; (void)out_size; (void)ws_size;
  const float* x   = (const float*)d_in[0];
  const float* gam = (const float*)d_in[1];
  const float* bet = (const float*)d_in[2];
  const float* wq  = (const float*)d_in[3];
  const float* bq  = (const float*)d_in[4];
  const float* wp  = (const float*)d_in[5];
  const float* bp  = (const float*)d_in[6];
  float* out = (float*)d_out;

  bf16* ws  = (bf16*)d_ws;
  bf16* ht  = ws;              // [16][1024][512]   (reused as attention output)
  bf16* qT  = ws + 8388608;    // [128][1024][64]
  bf16* kT  = ws + 16777216;   // [128][1024][64]
  bf16* vv  = ws + 25165824;   // [128][64][1024]
  bf16* wqb = ws + 33554432;   // [1536][512]
  bf16* wpb = ws + 34340864;   // [512][512]

  k_wconv<<<1024, 256, 0, stream>>>(wq, wp, wqb, wpb);
  k_gnorm<<<dim3(32, 16), 256, 0, stream>>>(x, gam, bet, ht);
  k_gemm<0><<<dim3(8, 12, 16), 256, 0, stream>>>(wqb, ht, bq, qT, kT, vv, nullptr, nullptr);
  k_attn<<<dim3(4, 8, 16), 512, 0, stream>>>(qT, kT, vv, ht);
  k_gemm<1><<<dim3(8, 4, 16), 256, 0, stream>>>(wpb, ht, bp, nullptr, nullptr, nullptr, x, out);
}